// Round 10
// baseline (1206.630 us; speedup 1.0000x reference)
//
#include <hip/hip_runtime.h>
#include <hip/hip_fp16.h>

#define T_TOK 16384
#define C_DIM 1024
#define F_DIM 4096
#define E_NUM 8

typedef _Float16 half8 __attribute__((ext_vector_type(8)));
typedef _Float16 half4v __attribute__((ext_vector_type(4)));
typedef float f32x4 __attribute__((ext_vector_type(4)));

// ---- workspace layout (bytes) ----
static constexpr size_t META_OFF  = 0;
static constexpr size_t XB_OFF    = 256;                                      // x fp16 [T][C]
static constexpr size_t W1T_OFF   = XB_OFF  + (size_t)2*T_TOK*C_DIM;          // w1^T fp16 [E][F][C]
static constexpr size_t W2T_OFF   = W1T_OFF + (size_t)2*E_NUM*C_DIM*F_DIM;    // w2^T fp16 [E][C][F]
static constexpr size_t HB_OFF    = W2T_OFF + (size_t)2*E_NUM*C_DIM*F_DIM;    // h fp16 [T*K][F]
static constexpr size_t YB_OFF    = HB_OFF  + (size_t)2*T_TOK*2*F_DIM;        // y fp16 [T*K][C]
static constexpr size_t TOK_OFF   = YB_OFF  + (size_t)2*T_TOK*2*C_DIM;        // int [E][T]
static constexpr size_t GATE_OFF  = TOK_OFF + (size_t)4*E_NUM*T_TOK;          // float [E][T]
static constexpr size_t TSLOT_OFF = GATE_OFF+ (size_t)4*E_NUM*T_TOK;          // int [T][2]
static constexpr size_t EPAIR_OFF = TSLOT_OFF + (size_t)4*T_TOK*2;            // int [T]   e0|(e1<<8)
static constexpr size_t GPAIR_OFF = EPAIR_OFF + (size_t)4*T_TOK;              // float2 [T]
static constexpr size_t WS_NEED   = GPAIR_OFF + (size_t)8*T_TOK;

__device__ __forceinline__ void async16(void* lds, const void* g) {
  __builtin_amdgcn_global_load_lds((const __attribute__((address_space(1))) unsigned int*)g,
                                   (__attribute__((address_space(3))) unsigned int*)lds,
                                   16, 0, 0);
}

// ---- transpose + cast: in fp32 [R][Cc] per expert -> out fp16 [Cc][R] ----
__global__ __launch_bounds__(256) void transpose_cast_kernel(const float* __restrict__ in,
                                                             _Float16* __restrict__ outp,
                                                             int R, int Cc) {
  __shared__ float tile[64][65];
  int e = blockIdx.z;
  const float* ip = in + (size_t)e * R * Cc;
  _Float16* op = outp + (size_t)e * R * Cc;
  int c0 = blockIdx.x * 64, r0 = blockIdx.y * 64;
  int tid = threadIdx.x;
  int lr = tid >> 4, lc = (tid & 15) * 4;
  #pragma unroll
  for (int d = 0; d < 4; ++d) {
    int row = lr + d * 16;
    float4 v = *(const float4*)(ip + (size_t)(r0 + row) * Cc + c0 + lc);
    tile[row][lc]     = v.x;
    tile[row][lc + 1] = v.y;
    tile[row][lc + 2] = v.z;
    tile[row][lc + 3] = v.w;
  }
  __syncthreads();
  int oc = tid >> 3, or8 = (tid & 7) * 8;
  #pragma unroll
  for (int d = 0; d < 2; ++d) {
    int c = oc + d * 32;
    half8 h;
    #pragma unroll
    for (int j = 0; j < 8; ++j) h[j] = (_Float16)tile[or8 + j][c];
    *(half8*)(op + (size_t)(c0 + c) * R + r0 + or8) = h;
  }
}

// ---- router (+ fused x fp32->fp16 cast): fp64 logits, top-2, NO atomics ----
__global__ __launch_bounds__(256) void router_kernel(const float* __restrict__ x,
                                                     const float* __restrict__ rw,
                                                     int* __restrict__ epair,
                                                     float2* __restrict__ gpair,
                                                     _Float16* __restrict__ xb) {
  int wv = threadIdx.x >> 6, l = threadIdx.x & 63;
  int t = blockIdx.x * 4 + wv;
  const float* xr = x + (size_t)t * C_DIM;
  double acc[E_NUM] = {};
  #pragma unroll
  for (int j = 0; j < 4; ++j) {
    float4 xv = *(const float4*)(xr + j * 256 + l * 4);
    half4v hv;
    hv[0] = (_Float16)xv.x; hv[1] = (_Float16)xv.y;
    hv[2] = (_Float16)xv.z; hv[3] = (_Float16)xv.w;
    *(half4v*)(xb + (size_t)t * C_DIM + j * 256 + l * 4) = hv;
    #pragma unroll
    for (int e = 0; e < E_NUM; ++e) {
      float4 w4 = *(const float4*)(rw + (size_t)e * C_DIM + j * 256 + l * 4);
      acc[e] += (double)xv.x * w4.x + (double)xv.y * w4.y +
                (double)xv.z * w4.z + (double)xv.w * w4.w;
    }
  }
  #pragma unroll
  for (int e = 0; e < E_NUM; ++e)
    #pragma unroll
    for (int off = 32; off; off >>= 1)
      acc[e] += __shfl_xor(acc[e], off, 64);

  if (l == 0) {
    double m = acc[0];
    #pragma unroll
    for (int e = 1; e < E_NUM; ++e) m = acc[e] > m ? acc[e] : m;
    double p[E_NUM], s = 0.0;
    #pragma unroll
    for (int e = 0; e < E_NUM; ++e) { p[e] = exp(acc[e] - m); s += p[e]; }
    int i0 = 0; double b0 = p[0];
    #pragma unroll
    for (int e = 1; e < E_NUM; ++e) if (p[e] > b0) { b0 = p[e]; i0 = e; }
    int i1 = -1; double b1v = -1.0;
    #pragma unroll
    for (int e = 0; e < E_NUM; ++e) if (e != i0 && p[e] > b1v) { b1v = p[e]; i1 = e; }
    double q0 = b0 / s, q1 = b1v / s;
    double den = q0 + q1 + 1e-9;
    epair[t] = i0 | (i1 << 8);
    gpair[t] = make_float2((float)(q0 / den), (float)(q1 / den));
  }
}

// ---- assign: per-expert ordered compaction, atomic-free (R7-proven) ----
__global__ __launch_bounds__(1024) void assign_kernel(const int* __restrict__ epair,
                                                      const float2* __restrict__ gpair,
                                                      int* __restrict__ counts,
                                                      int* __restrict__ tok,
                                                      float* __restrict__ gate,
                                                      int* __restrict__ tslot) {
  __shared__ int wsum[16];
  __shared__ int wbase[16];
  __shared__ int stot;
  int myE = blockIdx.x;
  int tid = threadIdx.x, wid = tid >> 6, lane = tid & 63;
  int base = 0;
  for (int it = 0; it < (T_TOK * 2) / 1024; ++it) {
    int idx = it * 1024 + tid;
    int t = idx >> 1, k = idx & 1;
    int ep = epair[t];
    int e = (k ? (ep >> 8) : ep) & 0xff;
    bool f = (e == myE);
    unsigned long long mask = __ballot(f);
    int lanep = __popcll(mask & ((1ull << lane) - 1ull));
    if (lane == 0) wsum[wid] = __popcll(mask);
    __syncthreads();
    if (tid == 0) {
      int s = 0;
      #pragma unroll
      for (int i = 0; i < 16; ++i) { wbase[i] = s; s += wsum[i]; }
      stot = s;
    }
    __syncthreads();
    if (f) {
      int slot = base + wbase[wid] + lanep;
      float2 g = gpair[t];
      tok[myE * T_TOK + slot] = t;
      gate[myE * T_TOK + slot] = k ? g.y : g.x;
      tslot[idx] = (myE << 24) | slot;
    }
    base += stot;
  }
  if (tid == 0) counts[myE] = base;
}

// ---- prefix sums: rowOff (meta[8..16]) and 128-row tileOff (meta[17..25]) ----
__global__ void plan_kernel(int* meta) {
  if (threadIdx.x == 0 && blockIdx.x == 0) {
    int ro = 0, to = 0;
    meta[8] = 0; meta[17] = 0;
    for (int e = 0; e < E_NUM; ++e) {
      int c = meta[e];
      ro += c; to += (c + 127) >> 7;
      meta[9 + e] = ro; meta[18 + e] = to;
    }
  }
}

// ============================================================================
// T3-minimum grouped GEMMs (guide's verified 2ph recipe, m248v2/m230):
// 128x128 tile, BK=64, 4 waves, DOUBLE-buffered LDS (64.5 KiB -> 2 blocks/CU),
// ONE barrier per K-step: {issue 8 gload_lds -> buf^1; ds_read+MFMA buf;
// __syncthreads (drains vmcnt AFTER compute); swap}. The just-issued loads
// ride out HBM/L2 latency under the current step's compute instead of a
// zero-distance drain (R5-R9 structure paid full latency per step).
// Zero-conflict involution swizzle (R2). No setprio (T5 null on lockstep,
// m190). NO waves/EU in __launch_bounds__ (R4 spill lesson).
// Block ordering: XCD chunk -> 8-mt bands x all nt (L2 reuse).
// ============================================================================

// ---- grouped GEMM1: h = gelu(x[tok] @ w1[e] + b1[e]) ----
__global__ __launch_bounds__(256) void gemm1_kernel(const _Float16* __restrict__ xb,
                                                    const _Float16* __restrict__ w1t,
                                                    const float* __restrict__ b1,
                                                    _Float16* __restrict__ hbuf,
                                                    const int* __restrict__ tok,
                                                    const int* __restrict__ meta) {
  __shared__ _Float16 smem[32768];   // 2 bufs x (A 16 KB + B 16 KB)
  __shared__ int tokLds[128];

  // XCD swizzle (nwg=8448, chunk 1056) + 8mt x 32nt banding
  int bid = blockIdx.x;
  int swz = (bid & 7) * 1056 + (bid >> 3);
  int band = swz >> 8, rem = swz & 255;
  int nt = rem >> 3;
  int mt = band * 8 + (rem & 7);
  if (mt >= meta[17 + E_NUM]) return;
  int e = 0;
  while (mt >= meta[18 + e]) ++e;
  int ne = meta[e];
  int r0 = (mt - meta[17 + e]) << 7;
  int valid = ne - r0; if (valid > 128) valid = 128;

  int tid = threadIdx.x;
  if (tid < 128) {
    int r = tid < valid ? tid : valid - 1;
    tokLds[tid] = tok[e * T_TOK + r0 + r];
  }
  __syncthreads();

  // staging: thread -> (row = tid>>2 [+64], chunk-slot = tid&3)
  int row = tid >> 2, c4 = tid & 3;
  int ch = c4 ^ ((row >> 1) & 3);             // involution; (row+64)>>1 ≡ row>>1 (mod 4)
  const _Float16* aSrc0 = xb + (size_t)tokLds[row] * C_DIM + ch * 8;
  const _Float16* aSrc1 = xb + (size_t)tokLds[row + 64] * C_DIM + ch * 8;
  const _Float16* bSrc0 = w1t + ((size_t)e * F_DIM + nt * 128 + row) * C_DIM + ch * 8;
  const _Float16* bSrc1 = bSrc0 + (size_t)64 * C_DIM;

  char* SM = (char*)smem;

  int w0 = tid >> 6, l = tid & 63;
  int wm = w0 >> 1, wn = w0 & 1;
  int rl = l & 15, q = l >> 4;
  int swq = (q ^ ((rl >> 1) & 3)) * 16;
  int aBy = wm * 4096 + rl * 64 + swq;            // + ks*8192 + m*1024
  int bBy = 16384 + wn * 4096 + rl * 64 + swq;    // + ks*8192 + n*1024

  // prologue: stage tile 0 -> buf0, drain
  {
    char* d0 = SM + (size_t)tid * 16;
    async16(d0,          aSrc0);      async16(d0 + 4096,  aSrc1);
    async16(d0 + 8192,   aSrc0 + 32); async16(d0 + 12288, aSrc1 + 32);
    async16(d0 + 16384,  bSrc0);      async16(d0 + 20480, bSrc1);
    async16(d0 + 24576,  bSrc0 + 32); async16(d0 + 28672, bSrc1 + 32);
  }
  __syncthreads();

  f32x4 acc[4][4] = {};
  constexpr int NT = C_DIM / 64;   // 16
  int cur = 0;
  for (int kt = 0; kt < NT; ++kt) {
    // issue next tile into the other buffer (no wait here)
    int kn = (kt + 1 < NT ? kt + 1 : kt) * 64;
    char* dn = SM + (cur ^ 1) * 32768 + (size_t)tid * 16;
    async16(dn,          aSrc0 + kn);      async16(dn + 4096,  aSrc1 + kn);
    async16(dn + 8192,   aSrc0 + kn + 32); async16(dn + 12288, aSrc1 + kn + 32);
    async16(dn + 16384,  bSrc0 + kn);      async16(dn + 20480, bSrc1 + kn);
    async16(dn + 24576,  bSrc0 + kn + 32); async16(dn + 28672, bSrc1 + kn + 32);
    // compute current tile while loads fly
    const char* Tb = (const char*)SM + cur * 32768;
    #pragma unroll
    for (int ks = 0; ks < 2; ++ks) {
      half8 af[4], bf[4];
      #pragma unroll
      for (int m = 0; m < 4; ++m)
        af[m] = *(const half8*)(Tb + ks * 8192 + aBy + m * 1024);
      #pragma unroll
      for (int n = 0; n < 4; ++n)
        bf[n] = *(const half8*)(Tb + ks * 8192 + bBy + n * 1024);
      #pragma unroll
      for (int m = 0; m < 4; ++m)
        #pragma unroll
        for (int n = 0; n < 4; ++n)
          acc[m][n] = __builtin_amdgcn_mfma_f32_16x16x32_f16(af[m], bf[n], acc[m][n], 0, 0, 0);
    }
    __syncthreads();   // single barrier: drains vmcnt (next tile landed) + lgkm
    cur ^= 1;
  }

  int hbase = meta[8 + e] + r0;
  float bv[4];
  #pragma unroll
  for (int n = 0; n < 4; ++n)
    bv[n] = b1[(size_t)e * F_DIM + nt * 128 + wn * 64 + n * 16 + rl];
  #pragma unroll
  for (int m = 0; m < 4; ++m) {
    int rb = wm * 64 + m * 16 + q * 4;
    #pragma unroll
    for (int n = 0; n < 4; ++n) {
      int col = nt * 128 + wn * 64 + n * 16 + rl;
      #pragma unroll
      for (int r = 0; r < 4; ++r) {
        int rr = rb + r;
        if (rr < valid) {
          float pre = acc[m][n][r] + bv[n];
          float g = 0.5f * pre * (1.0f + erff(pre * 0.70710678118654752f));
          hbuf[(size_t)(hbase + rr) * F_DIM + col] = (_Float16)g;
        }
      }
    }
  }
}

// ---- grouped GEMM2: ybuf = gate * (h @ w2[e] + b2[e]) ----
__global__ __launch_bounds__(256) void gemm2_kernel(const _Float16* __restrict__ hbuf,
                                                    const _Float16* __restrict__ w2t,
                                                    const float* __restrict__ b2,
                                                    _Float16* __restrict__ ybuf,
                                                    const float* __restrict__ gate,
                                                    const int* __restrict__ meta) {
  __shared__ _Float16 smem[32768];   // 2 bufs x (A 16 KB + B 16 KB)
  __shared__ float gateLds[128];

  // XCD swizzle (nwg=2112, chunk 264) + 8mt x 8nt banding
  int bid = blockIdx.x;
  int swz = (bid & 7) * 264 + (bid >> 3);
  int band = swz >> 6, rem = swz & 63;
  int nt = rem >> 3;
  int mt = band * 8 + (rem & 7);
  if (mt >= meta[17 + E_NUM]) return;
  int e = 0;
  while (mt >= meta[18 + e]) ++e;
  int ne = meta[e];
  int r0 = (mt - meta[17 + e]) << 7;
  int valid = ne - r0; if (valid > 128) valid = 128;
  int hbase = meta[8 + e] + r0;

  int tid = threadIdx.x;
  if (tid < 128) {
    int r = tid < valid ? tid : valid - 1;
    gateLds[tid] = gate[e * T_TOK + r0 + r];
  }
  __syncthreads();

  int row = tid >> 2, c4 = tid & 3;
  int ch = c4 ^ ((row >> 1) & 3);
  int rcA0 = row      < valid ? row      : valid - 1;
  int rcA1 = row + 64 < valid ? row + 64 : valid - 1;
  const _Float16* aSrc0 = hbuf + (size_t)(hbase + rcA0) * F_DIM + ch * 8;
  const _Float16* aSrc1 = hbuf + (size_t)(hbase + rcA1) * F_DIM + ch * 8;
  const _Float16* bSrc0 = w2t + ((size_t)e * C_DIM + nt * 128 + row) * F_DIM + ch * 8;
  const _Float16* bSrc1 = bSrc0 + (size_t)64 * F_DIM;

  char* SM = (char*)smem;

  int w0 = tid >> 6, l = tid & 63;
  int wm = w0 >> 1, wn = w0 & 1;
  int rl = l & 15, q = l >> 4;
  int swq = (q ^ ((rl >> 1) & 3)) * 16;
  int aBy = wm * 4096 + rl * 64 + swq;
  int bBy = 16384 + wn * 4096 + rl * 64 + swq;

  {
    char* d0 = SM + (size_t)tid * 16;
    async16(d0,          aSrc0);      async16(d0 + 4096,  aSrc1);
    async16(d0 + 8192,   aSrc0 + 32); async16(d0 + 12288, aSrc1 + 32);
    async16(d0 + 16384,  bSrc0);      async16(d0 + 20480, bSrc1);
    async16(d0 + 24576,  bSrc0 + 32); async16(d0 + 28672, bSrc1 + 32);
  }
  __syncthreads();

  f32x4 acc[4][4] = {};
  constexpr int NT = F_DIM / 64;   // 64
  int cur = 0;
  for (int kt = 0; kt < NT; ++kt) {
    int kn = (kt + 1 < NT ? kt + 1 : kt) * 64;
    char* dn = SM + (cur ^ 1) * 32768 + (size_t)tid * 16;
    async16(dn,          aSrc0 + kn);      async16(dn + 4096,  aSrc1 + kn);
    async16(dn + 8192,   aSrc0 + kn + 32); async16(dn + 12288, aSrc1 + kn + 32);
    async16(dn + 16384,  bSrc0 + kn);      async16(dn + 20480, bSrc1 + kn);
    async16(dn + 24576,  bSrc0 + kn + 32); async16(dn + 28672, bSrc1 + kn + 32);
    const char* Tb = (const char*)SM + cur * 32768;
    #pragma unroll
    for (int ks = 0; ks < 2; ++ks) {
      half8 af[4], bf[4];
      #pragma unroll
      for (int m = 0; m < 4; ++m)
        af[m] = *(const half8*)(Tb + ks * 8192 + aBy + m * 1024);
      #pragma unroll
      for (int n = 0; n < 4; ++n)
        bf[n] = *(const half8*)(Tb + ks * 8192 + bBy + n * 1024);
      #pragma unroll
      for (int m = 0; m < 4; ++m)
        #pragma unroll
        for (int n = 0; n < 4; ++n)
          acc[m][n] = __builtin_amdgcn_mfma_f32_16x16x32_f16(af[m], bf[n], acc[m][n], 0, 0, 0);
    }
    __syncthreads();
    cur ^= 1;
  }

  float bv[4];
  #pragma unroll
  for (int n = 0; n < 4; ++n)
    bv[n] = b2[(size_t)e * C_DIM + nt * 128 + wn * 64 + n * 16 + rl];
  #pragma unroll
  for (int m = 0; m < 4; ++m) {
    int rb = wm * 64 + m * 16 + q * 4;
    #pragma unroll
    for (int n = 0; n < 4; ++n) {
      int col = nt * 128 + wn * 64 + n * 16 + rl;
      #pragma unroll
      for (int r = 0; r < 4; ++r) {
        int rr = rb + r;
        if (rr < valid) {
          float val = gateLds[rr] * (acc[m][n][r] + bv[n]);
          ybuf[(size_t)(hbase + rr) * C_DIM + col] = (_Float16)val;
        }
      }
    }
  }
}

// ---- combine: out[t] = y(slot0) + y(slot1) ----
__global__ __launch_bounds__(256) void combine_kernel(const _Float16* __restrict__ ybuf,
                                                      const int* __restrict__ tslot,
                                                      const int* __restrict__ meta,
                                                      float* __restrict__ out) {
  int gid = blockIdx.x * 256 + threadIdx.x;
  int t = gid >> 7;
  int cc = (gid & 127) << 3;
  int s0 = tslot[t * 2], s1 = tslot[t * 2 + 1];
  size_t r0 = (size_t)meta[8 + (s0 >> 24)] + (s0 & 0xFFFFFF);
  size_t r1 = (size_t)meta[8 + (s1 >> 24)] + (s1 & 0xFFFFFF);
  half8 y0 = *(const half8*)(ybuf + r0 * C_DIM + cc);
  half8 y1 = *(const half8*)(ybuf + r1 * C_DIM + cc);
  float4 o0, o1;
  o0.x = (float)y0[0] + (float)y1[0];
  o0.y = (float)y0[1] + (float)y1[1];
  o0.z = (float)y0[2] + (float)y1[2];
  o0.w = (float)y0[3] + (float)y1[3];
  o1.x = (float)y0[4] + (float)y1[4];
  o1.y = (float)y0[5] + (float)y1[5];
  o1.z = (float)y0[6] + (float)y1[6];
  o1.w = (float)y0[7] + (float)y1[7];
  *(float4*)(out + (size_t)t * C_DIM + cc) = o0;
  *(float4*)(out + (size_t)t * C_DIM + cc + 4) = o1;
}

extern "C" void kernel_launch(void* const* d_in, const int* in_sizes, int n_in,
                              void* d_out, int out_size, void* d_ws, size_t ws_size,
                              hipStream_t stream) {
  (void)in_sizes; (void)n_in; (void)out_size;
  if (!d_ws || ws_size < WS_NEED) return;  // need ~481 MiB scratch

  const float* x  = (const float*)d_in[0];
  const float* rw = (const float*)d_in[1];
  const float* w1 = (const float*)d_in[2];
  const float* b1 = (const float*)d_in[3];
  const float* w2 = (const float*)d_in[4];
  const float* b2 = (const float*)d_in[5];
  float* out = (float*)d_out;

  char* ws = (char*)d_ws;
  int*       meta  = (int*)(ws + META_OFF);
  _Float16*  xb    = (_Float16*)(ws + XB_OFF);
  _Float16*  w1t   = (_Float16*)(ws + W1T_OFF);
  _Float16*  w2t   = (_Float16*)(ws + W2T_OFF);
  _Float16*  hbuf  = (_Float16*)(ws + HB_OFF);
  _Float16*  ybuf  = (_Float16*)(ws + YB_OFF);
  int*       tok   = (int*)(ws + TOK_OFF);
  float*     gate  = (float*)(ws + GATE_OFF);
  int*       tslot = (int*)(ws + TSLOT_OFF);
  int*       epair = (int*)(ws + EPAIR_OFF);
  float2*    gpair = (float2*)(ws + GPAIR_OFF);

  hipMemsetAsync(meta, 0, 256, stream);

  transpose_cast_kernel<<<dim3(F_DIM / 64, C_DIM / 64, E_NUM), 256, 0, stream>>>(w1, w1t, C_DIM, F_DIM);
  transpose_cast_kernel<<<dim3(C_DIM / 64, F_DIM / 64, E_NUM), 256, 0, stream>>>(w2, w2t, F_DIM, C_DIM);
  router_kernel<<<T_TOK / 4, 256, 0, stream>>>(x, rw, epair, gpair, xb);
  assign_kernel<<<E_NUM, 1024, 0, stream>>>(epair, gpair, meta, tok, gate, tslot);
  plan_kernel<<<1, 64, 0, stream>>>(meta);

  // max 128-row M-tiles = T*K/128 + (E-1) = 263 -> 264 (%8==0 for XCD swizzle)
  gemm1_kernel<<<264 * 32, 256, 0, stream>>>(xb, w1t, b1, hbuf, tok, meta);
  gemm2_kernel<<<264 * 8, 256, 0, stream>>>(hbuf, w2t, b2, ybuf, gate, meta);
  combine_kernel<<<(T_TOK * (C_DIM / 8)) / 256, 256, 0, stream>>>(ybuf, tslot, meta, out);
}

// Round 11
// 956.516 us; speedup vs baseline: 1.2615x; 1.2615x over previous
//
#include <hip/hip_runtime.h>
#include <hip/hip_fp16.h>

#define T_TOK 16384
#define C_DIM 1024
#define F_DIM 4096
#define E_NUM 8

typedef _Float16 half8 __attribute__((ext_vector_type(8)));
typedef _Float16 half4v __attribute__((ext_vector_type(4)));
typedef float f32x4 __attribute__((ext_vector_type(4)));

// ---- workspace layout (bytes) ----
static constexpr size_t META_OFF  = 0;
static constexpr size_t XB_OFF    = 256;                                      // x fp16 [T][C]
static constexpr size_t W1T_OFF   = XB_OFF  + (size_t)2*T_TOK*C_DIM;          // w1^T fp16 [E][F][C]
static constexpr size_t W2T_OFF   = W1T_OFF + (size_t)2*E_NUM*C_DIM*F_DIM;    // w2^T fp16 [E][C][F]
static constexpr size_t HB_OFF    = W2T_OFF + (size_t)2*E_NUM*C_DIM*F_DIM;    // h fp16 [T*K][F]
static constexpr size_t YB_OFF    = HB_OFF  + (size_t)2*T_TOK*2*F_DIM;        // y fp16 [T*K][C]
static constexpr size_t TOK_OFF   = YB_OFF  + (size_t)2*T_TOK*2*C_DIM;        // int [E][T]
static constexpr size_t GATE_OFF  = TOK_OFF + (size_t)4*E_NUM*T_TOK;          // float [E][T]
static constexpr size_t TSLOT_OFF = GATE_OFF+ (size_t)4*E_NUM*T_TOK;          // int [T][2]
static constexpr size_t EPAIR_OFF = TSLOT_OFF + (size_t)4*T_TOK*2;            // int [T]   e0|(e1<<8)
static constexpr size_t GPAIR_OFF = EPAIR_OFF + (size_t)4*T_TOK;              // float2 [T]
static constexpr size_t WS_NEED   = GPAIR_OFF + (size_t)8*T_TOK;

__device__ __forceinline__ void async16(void* lds, const void* g) {
  __builtin_amdgcn_global_load_lds((const __attribute__((address_space(1))) unsigned int*)g,
                                   (__attribute__((address_space(3))) unsigned int*)lds,
                                   16, 0, 0);
}

// de-convoy: phase-shift co-resident blocks (bids ~256 apart share a CU round)
__device__ __forceinline__ void stagger(int bid) {
  int s = (bid >> 8) & 3;
  for (int i = 0; i < s * 5; ++i) __builtin_amdgcn_s_sleep(2);  // ~s*640 cyc
}

// ---- transpose + cast: in fp32 [R][Cc] per expert -> out fp16 [Cc][R] ----
__global__ __launch_bounds__(256) void transpose_cast_kernel(const float* __restrict__ in,
                                                             _Float16* __restrict__ outp,
                                                             int R, int Cc) {
  __shared__ float tile[64][65];
  int e = blockIdx.z;
  const float* ip = in + (size_t)e * R * Cc;
  _Float16* op = outp + (size_t)e * R * Cc;
  int c0 = blockIdx.x * 64, r0 = blockIdx.y * 64;
  int tid = threadIdx.x;
  int lr = tid >> 4, lc = (tid & 15) * 4;
  #pragma unroll
  for (int d = 0; d < 4; ++d) {
    int row = lr + d * 16;
    float4 v = *(const float4*)(ip + (size_t)(r0 + row) * Cc + c0 + lc);
    tile[row][lc]     = v.x;
    tile[row][lc + 1] = v.y;
    tile[row][lc + 2] = v.z;
    tile[row][lc + 3] = v.w;
  }
  __syncthreads();
  int oc = tid >> 3, or8 = (tid & 7) * 8;
  #pragma unroll
  for (int d = 0; d < 2; ++d) {
    int c = oc + d * 32;
    half8 h;
    #pragma unroll
    for (int j = 0; j < 8; ++j) h[j] = (_Float16)tile[or8 + j][c];
    *(half8*)(op + (size_t)(c0 + c) * R + r0 + or8) = h;
  }
}

// ---- router (+ fused x fp32->fp16 cast): fp64 logits, top-2, NO atomics ----
__global__ __launch_bounds__(256) void router_kernel(const float* __restrict__ x,
                                                     const float* __restrict__ rw,
                                                     int* __restrict__ epair,
                                                     float2* __restrict__ gpair,
                                                     _Float16* __restrict__ xb) {
  int wv = threadIdx.x >> 6, l = threadIdx.x & 63;
  int t = blockIdx.x * 4 + wv;
  const float* xr = x + (size_t)t * C_DIM;
  double acc[E_NUM] = {};
  #pragma unroll
  for (int j = 0; j < 4; ++j) {
    float4 xv = *(const float4*)(xr + j * 256 + l * 4);
    half4v hv;
    hv[0] = (_Float16)xv.x; hv[1] = (_Float16)xv.y;
    hv[2] = (_Float16)xv.z; hv[3] = (_Float16)xv.w;
    *(half4v*)(xb + (size_t)t * C_DIM + j * 256 + l * 4) = hv;
    #pragma unroll
    for (int e = 0; e < E_NUM; ++e) {
      float4 w4 = *(const float4*)(rw + (size_t)e * C_DIM + j * 256 + l * 4);
      acc[e] += (double)xv.x * w4.x + (double)xv.y * w4.y +
                (double)xv.z * w4.z + (double)xv.w * w4.w;
    }
  }
  #pragma unroll
  for (int e = 0; e < E_NUM; ++e)
    #pragma unroll
    for (int off = 32; off; off >>= 1)
      acc[e] += __shfl_xor(acc[e], off, 64);

  if (l == 0) {
    double m = acc[0];
    #pragma unroll
    for (int e = 1; e < E_NUM; ++e) m = acc[e] > m ? acc[e] : m;
    double p[E_NUM], s = 0.0;
    #pragma unroll
    for (int e = 0; e < E_NUM; ++e) { p[e] = exp(acc[e] - m); s += p[e]; }
    int i0 = 0; double b0 = p[0];
    #pragma unroll
    for (int e = 1; e < E_NUM; ++e) if (p[e] > b0) { b0 = p[e]; i0 = e; }
    int i1 = -1; double b1v = -1.0;
    #pragma unroll
    for (int e = 0; e < E_NUM; ++e) if (e != i0 && p[e] > b1v) { b1v = p[e]; i1 = e; }
    double q0 = b0 / s, q1 = b1v / s;
    double den = q0 + q1 + 1e-9;
    epair[t] = i0 | (i1 << 8);
    gpair[t] = make_float2((float)(q0 / den), (float)(q1 / den));
  }
}

// ---- assign: per-expert ordered compaction, atomic-free (R7-proven) ----
__global__ __launch_bounds__(1024) void assign_kernel(const int* __restrict__ epair,
                                                      const float2* __restrict__ gpair,
                                                      int* __restrict__ counts,
                                                      int* __restrict__ tok,
                                                      float* __restrict__ gate,
                                                      int* __restrict__ tslot) {
  __shared__ int wsum[16];
  __shared__ int wbase[16];
  __shared__ int stot;
  int myE = blockIdx.x;
  int tid = threadIdx.x, wid = tid >> 6, lane = tid & 63;
  int base = 0;
  for (int it = 0; it < (T_TOK * 2) / 1024; ++it) {
    int idx = it * 1024 + tid;
    int t = idx >> 1, k = idx & 1;
    int ep = epair[t];
    int e = (k ? (ep >> 8) : ep) & 0xff;
    bool f = (e == myE);
    unsigned long long mask = __ballot(f);
    int lanep = __popcll(mask & ((1ull << lane) - 1ull));
    if (lane == 0) wsum[wid] = __popcll(mask);
    __syncthreads();
    if (tid == 0) {
      int s = 0;
      #pragma unroll
      for (int i = 0; i < 16; ++i) { wbase[i] = s; s += wsum[i]; }
      stot = s;
    }
    __syncthreads();
    if (f) {
      int slot = base + wbase[wid] + lanep;
      float2 g = gpair[t];
      tok[myE * T_TOK + slot] = t;
      gate[myE * T_TOK + slot] = k ? g.y : g.x;
      tslot[idx] = (myE << 24) | slot;
    }
    base += stot;
  }
  if (tid == 0) counts[myE] = base;
}

// ---- prefix sums: rowOff (meta[8..16]) and 128-row tileOff (meta[17..25]) ----
__global__ void plan_kernel(int* meta) {
  if (threadIdx.x == 0 && blockIdx.x == 0) {
    int ro = 0, to = 0;
    meta[8] = 0; meta[17] = 0;
    for (int e = 0; e < E_NUM; ++e) {
      int c = meta[e];
      ro += c; to += (c + 127) >> 7;
      meta[9 + e] = ro; meta[18 + e] = to;
    }
  }
}

// ============================================================================
// R7-proven grouped GEMM structure for BOTH GEMMs now: 128x256 tile, BK=64,
// 8 waves (2M x 4N), single-buffer LDS 48.5 KiB -> 3 blocks/CU, 2-barrier
// K-loop, compiler-managed waits. NEW: start-stagger de-convoys co-resident
// blocks (identical barrier-locked loops otherwise issue memory bursts in
// sync -> fabric serializes -> m114 overlap never materializes; explains
// MfmaUtil 26% when arithmetic predicts ~95% at 3-4 resident blocks).
// Zero-conflict involution swizzle (R2). No waves/EU bound (R4 spill).
// Block ordering: XCD chunk -> 8-mt bands x all nt (L2 reuse).
// ============================================================================

// ---- grouped GEMM1: h = gelu(x[tok] @ w1[e] + b1[e]) ----
__global__ __launch_bounds__(512) void gemm1_kernel(const _Float16* __restrict__ xb,
                                                    const _Float16* __restrict__ w1t,
                                                    const float* __restrict__ b1,
                                                    _Float16* __restrict__ hbuf,
                                                    const int* __restrict__ tok,
                                                    const int* __restrict__ meta) {
  __shared__ _Float16 smem[24576];   // A 16 KB (2ks x 128r x 64B) + B 32 KB (2ks x 256r x 64B)
  __shared__ int tokLds[128];

  int bid = blockIdx.x;
  int swz = (bid & 7) * 528 + (bid >> 3);
  int band = swz >> 7, rem = swz & 127;
  int nt = rem >> 3;
  int mt = band * 8 + (rem & 7);
  if (mt >= meta[17 + E_NUM]) return;
  stagger(bid);
  int e = 0;
  while (mt >= meta[18 + e]) ++e;
  int ne = meta[e];
  int r0 = (mt - meta[17 + e]) << 7;
  int valid = ne - r0; if (valid > 128) valid = 128;

  int tid = threadIdx.x;
  if (tid < 128) {
    int r = tid < valid ? tid : valid - 1;
    tokLds[tid] = tok[e * T_TOK + r0 + r];
  }
  __syncthreads();

  int row = tid >> 2, c4 = tid & 3;
  int ch = c4 ^ ((row >> 1) & 3);
  const _Float16* aSrc  = xb + (size_t)tokLds[row] * C_DIM + ch * 8;
  const _Float16* bSrc0 = w1t + ((size_t)e * F_DIM + nt * 256 + row) * C_DIM + ch * 8;
  const _Float16* bSrc1 = bSrc0 + (size_t)128 * C_DIM;

  char* SM = (char*)smem;
  char* dst = SM + (size_t)tid * 16;

  int w = tid >> 6, l = tid & 63;
  int wm = w >> 2, wn = w & 3;
  int rl = l & 15, q = l >> 4;
  int swq = (q ^ ((rl >> 1) & 3)) * 16;
  int aBy = wm * 4096 + rl * 64 + swq;
  int bBy = 16384 + wn * 4096 + rl * 64 + swq;

  f32x4 acc[4][4] = {};
  constexpr int NT = C_DIM / 64;   // 16
  for (int kt = 0; kt < NT; ++kt) {
    __syncthreads();
    int ko = kt * 64;
    async16(dst,          aSrc  + ko);
    async16(dst + 8192,   aSrc  + ko + 32);
    async16(dst + 16384,  bSrc0 + ko);
    async16(dst + 24576,  bSrc1 + ko);
    async16(dst + 32768,  bSrc0 + ko + 32);
    async16(dst + 40960,  bSrc1 + ko + 32);
    __syncthreads();
    #pragma unroll
    for (int ks = 0; ks < 2; ++ks) {
      half8 af[4], bf[4];
      #pragma unroll
      for (int m = 0; m < 4; ++m)
        af[m] = *(const half8*)(SM + ks * 8192 + aBy + m * 1024);
      #pragma unroll
      for (int n = 0; n < 4; ++n)
        bf[n] = *(const half8*)(SM + ks * 16384 + bBy + n * 1024);
      #pragma unroll
      for (int m = 0; m < 4; ++m)
        #pragma unroll
        for (int n = 0; n < 4; ++n)
          acc[m][n] = __builtin_amdgcn_mfma_f32_16x16x32_f16(af[m], bf[n], acc[m][n], 0, 0, 0);
    }
  }

  int hbase = meta[8 + e] + r0;
  float bv[4];
  #pragma unroll
  for (int n = 0; n < 4; ++n)
    bv[n] = b1[(size_t)e * F_DIM + nt * 256 + wn * 64 + n * 16 + rl];
  #pragma unroll
  for (int m = 0; m < 4; ++m) {
    int rb = wm * 64 + m * 16 + q * 4;
    #pragma unroll
    for (int n = 0; n < 4; ++n) {
      int col = nt * 256 + wn * 64 + n * 16 + rl;
      #pragma unroll
      for (int r = 0; r < 4; ++r) {
        int rr = rb + r;
        if (rr < valid) {
          float pre = acc[m][n][r] + bv[n];
          float g = 0.5f * pre * (1.0f + erff(pre * 0.70710678118654752f));
          hbuf[(size_t)(hbase + rr) * F_DIM + col] = (_Float16)g;
        }
      }
    }
  }
}

// ---- grouped GEMM2: ybuf = gate * (h @ w2[e] + b2[e]) ----
// NOW the same 128x256 geometry as gemm1 (was 128x128): halves A re-reads.
__global__ __launch_bounds__(512) void gemm2_kernel(const _Float16* __restrict__ hbuf,
                                                    const _Float16* __restrict__ w2t,
                                                    const float* __restrict__ b2,
                                                    _Float16* __restrict__ ybuf,
                                                    const float* __restrict__ gate,
                                                    const int* __restrict__ meta) {
  __shared__ _Float16 smem[24576];   // A 16 KB + B 32 KB
  __shared__ float gateLds[128];

  // XCD swizzle (nwg=1056, chunk 132) + 8mt x 4nt banding
  int bid = blockIdx.x;
  int swz = (bid & 7) * 132 + (bid >> 3);
  int band = swz >> 5, rem = swz & 31;
  int nt = rem >> 3;
  int mt = band * 8 + (rem & 7);
  if (mt >= meta[17 + E_NUM]) return;
  stagger(bid);
  int e = 0;
  while (mt >= meta[18 + e]) ++e;
  int ne = meta[e];
  int r0 = (mt - meta[17 + e]) << 7;
  int valid = ne - r0; if (valid > 128) valid = 128;
  int hbase = meta[8 + e] + r0;

  int tid = threadIdx.x;
  if (tid < 128) {
    int r = tid < valid ? tid : valid - 1;
    gateLds[tid] = gate[e * T_TOK + r0 + r];
  }
  __syncthreads();

  int row = tid >> 2, c4 = tid & 3;           // row 0..127
  int ch = c4 ^ ((row >> 1) & 3);
  int rcA = row < valid ? row : valid - 1;
  const _Float16* aSrc  = hbuf + (size_t)(hbase + rcA) * F_DIM + ch * 8;
  const _Float16* bSrc0 = w2t + ((size_t)e * C_DIM + nt * 256 + row) * F_DIM + ch * 8;
  const _Float16* bSrc1 = bSrc0 + (size_t)128 * F_DIM;

  char* SM = (char*)smem;
  char* dst = SM + (size_t)tid * 16;

  int w = tid >> 6, l = tid & 63;
  int wm = w >> 2, wn = w & 3;
  int rl = l & 15, q = l >> 4;
  int swq = (q ^ ((rl >> 1) & 3)) * 16;
  int aBy = wm * 4096 + rl * 64 + swq;
  int bBy = 16384 + wn * 4096 + rl * 64 + swq;

  f32x4 acc[4][4] = {};
  constexpr int NT = F_DIM / 64;   // 64
  for (int kt = 0; kt < NT; ++kt) {
    __syncthreads();
    int ko = kt * 64;
    async16(dst,          aSrc  + ko);
    async16(dst + 8192,   aSrc  + ko + 32);
    async16(dst + 16384,  bSrc0 + ko);
    async16(dst + 24576,  bSrc1 + ko);
    async16(dst + 32768,  bSrc0 + ko + 32);
    async16(dst + 40960,  bSrc1 + ko + 32);
    __syncthreads();
    #pragma unroll
    for (int ks = 0; ks < 2; ++ks) {
      half8 af[4], bf[4];
      #pragma unroll
      for (int m = 0; m < 4; ++m)
        af[m] = *(const half8*)(SM + ks * 8192 + aBy + m * 1024);
      #pragma unroll
      for (int n = 0; n < 4; ++n)
        bf[n] = *(const half8*)(SM + ks * 16384 + bBy + n * 1024);
      #pragma unroll
      for (int m = 0; m < 4; ++m)
        #pragma unroll
        for (int n = 0; n < 4; ++n)
          acc[m][n] = __builtin_amdgcn_mfma_f32_16x16x32_f16(af[m], bf[n], acc[m][n], 0, 0, 0);
    }
  }

  float bv[4];
  #pragma unroll
  for (int n = 0; n < 4; ++n)
    bv[n] = b2[(size_t)e * C_DIM + nt * 256 + wn * 64 + n * 16 + rl];
  #pragma unroll
  for (int m = 0; m < 4; ++m) {
    int rb = wm * 64 + m * 16 + q * 4;
    #pragma unroll
    for (int n = 0; n < 4; ++n) {
      int col = nt * 256 + wn * 64 + n * 16 + rl;
      #pragma unroll
      for (int r = 0; r < 4; ++r) {
        int rr = rb + r;
        if (rr < valid) {
          float val = gateLds[rr] * (acc[m][n][r] + bv[n]);
          ybuf[(size_t)(hbase + rr) * C_DIM + col] = (_Float16)val;
        }
      }
    }
  }
}

// ---- combine: out[t] = y(slot0) + y(slot1) ----
__global__ __launch_bounds__(256) void combine_kernel(const _Float16* __restrict__ ybuf,
                                                      const int* __restrict__ tslot,
                                                      const int* __restrict__ meta,
                                                      float* __restrict__ out) {
  int gid = blockIdx.x * 256 + threadIdx.x;
  int t = gid >> 7;
  int cc = (gid & 127) << 3;
  int s0 = tslot[t * 2], s1 = tslot[t * 2 + 1];
  size_t r0 = (size_t)meta[8 + (s0 >> 24)] + (s0 & 0xFFFFFF);
  size_t r1 = (size_t)meta[8 + (s1 >> 24)] + (s1 & 0xFFFFFF);
  half8 y0 = *(const half8*)(ybuf + r0 * C_DIM + cc);
  half8 y1 = *(const half8*)(ybuf + r1 * C_DIM + cc);
  float4 o0, o1;
  o0.x = (float)y0[0] + (float)y1[0];
  o0.y = (float)y0[1] + (float)y1[1];
  o0.z = (float)y0[2] + (float)y1[2];
  o0.w = (float)y0[3] + (float)y1[3];
  o1.x = (float)y0[4] + (float)y1[4];
  o1.y = (float)y0[5] + (float)y1[5];
  o1.z = (float)y0[6] + (float)y1[6];
  o1.w = (float)y0[7] + (float)y1[7];
  *(float4*)(out + (size_t)t * C_DIM + cc) = o0;
  *(float4*)(out + (size_t)t * C_DIM + cc + 4) = o1;
}

extern "C" void kernel_launch(void* const* d_in, const int* in_sizes, int n_in,
                              void* d_out, int out_size, void* d_ws, size_t ws_size,
                              hipStream_t stream) {
  (void)in_sizes; (void)n_in; (void)out_size;
  if (!d_ws || ws_size < WS_NEED) return;  // need ~481 MiB scratch

  const float* x  = (const float*)d_in[0];
  const float* rw = (const float*)d_in[1];
  const float* w1 = (const float*)d_in[2];
  const float* b1 = (const float*)d_in[3];
  const float* w2 = (const float*)d_in[4];
  const float* b2 = (const float*)d_in[5];
  float* out = (float*)d_out;

  char* ws = (char*)d_ws;
  int*       meta  = (int*)(ws + META_OFF);
  _Float16*  xb    = (_Float16*)(ws + XB_OFF);
  _Float16*  w1t   = (_Float16*)(ws + W1T_OFF);
  _Float16*  w2t   = (_Float16*)(ws + W2T_OFF);
  _Float16*  hbuf  = (_Float16*)(ws + HB_OFF);
  _Float16*  ybuf  = (_Float16*)(ws + YB_OFF);
  int*       tok   = (int*)(ws + TOK_OFF);
  float*     gate  = (float*)(ws + GATE_OFF);
  int*       tslot = (int*)(ws + TSLOT_OFF);
  int*       epair = (int*)(ws + EPAIR_OFF);
  float2*    gpair = (float2*)(ws + GPAIR_OFF);

  hipMemsetAsync(meta, 0, 256, stream);

  transpose_cast_kernel<<<dim3(F_DIM / 64, C_DIM / 64, E_NUM), 256, 0, stream>>>(w1, w1t, C_DIM, F_DIM);
  transpose_cast_kernel<<<dim3(C_DIM / 64, F_DIM / 64, E_NUM), 256, 0, stream>>>(w2, w2t, F_DIM, C_DIM);
  router_kernel<<<T_TOK / 4, 256, 0, stream>>>(x, rw, epair, gpair, xb);
  assign_kernel<<<E_NUM, 1024, 0, stream>>>(epair, gpair, meta, tok, gate, tslot);
  plan_kernel<<<1, 64, 0, stream>>>(meta);

  // max 128-row M-tiles = T*K/128 + (E-1) = 263 -> 264 (%8==0 for XCD swizzle)
  gemm1_kernel<<<264 * 16, 512, 0, stream>>>(xb, w1t, b1, hbuf, tok, meta);
  gemm2_kernel<<<264 * 4, 512, 0, stream>>>(hbuf, w2t, b2, ybuf, gate, meta);
  combine_kernel<<<(T_TOK * (C_DIM / 8)) / 256, 256, 0, stream>>>(ybuf, tslot, meta, out);
}